// Round 17
// baseline (293.061 us; speedup 1.0000x reference)
//
#include <hip/hip_runtime.h>
#include <hip/hip_bf16.h>
#include <hip/hip_fp16.h>

#define FIN 256
#define HID 128
#define BSH 7            // bucket = dst >> 7 (128 nodes/bucket)
#define NBK_MAX 1024
#define EPB 4096         // edges per block in hist/pair kernels
#define WPAD 264         // 256 + 8 halfs row pad

typedef __attribute__((ext_vector_type(8))) _Float16 half8v;  // f16x8 MFMA frag (4 VGPRs)
typedef __attribute__((ext_vector_type(4))) float f32x4;      // MFMA acc

// ---------------- W1 -> fp16 (once) + bcnt zeroing + hs zero-row init ----------------
__global__ void k_whalf(const float* __restrict__ W1, _Float16* __restrict__ Wh,
                        int* __restrict__ bcnt, unsigned int* __restrict__ hs8,
                        int n, int total) {
    int i = blockIdx.x * 256 + threadIdx.x;
    if (i < total) Wh[i] = (_Float16)W1[i];
    if (blockIdx.x == 0) {
        #pragma unroll
        for (int j = 0; j < NBK_MAX; j += 256) bcnt[j + threadIdx.x] = 0;
        // zero row (index n) of each of the 8 group slices: 8 x 8 uints
        if (threadIdx.x < 64) {
            int g  = threadIdx.x >> 3;
            int fp = threadIdx.x & 7;
            hs8[((size_t)g * (n + 1) + n) * 8 + fp] = 0u;
        }
    }
}

// ---------------- bucket histogram via LDS ----------------
__global__ __launch_bounds__(256) void k_hist(const int* __restrict__ dst, int* __restrict__ bcnt,
                                              int nbk, int e) {
    __shared__ int cnt[NBK_MAX];
    int t = threadIdx.x;
    for (int b = t; b < nbk; b += 256) cnt[b] = 0;
    __syncthreads();
    int e0 = blockIdx.x * EPB;
    #pragma unroll
    for (int j = 0; j < EPB; j += 256) {
        int idx = e0 + j + t;
        if (idx < e) atomicAdd(&cnt[dst[idx] >> BSH], 1);
    }
    __syncthreads();
    for (int b = t; b < nbk; b += 256)
        if (cnt[b]) atomicAdd(&bcnt[b], cnt[b]);
}

// ---------------- bucket scan (single block) ----------------
__global__ __launch_bounds__(1024) void k_bscan(const int* __restrict__ bcnt, int* __restrict__ bo,
                                                int* __restrict__ bcur, int nbk, int e) {
    __shared__ int sm[1024];
    int t = threadIdx.x;
    int v = (t < nbk) ? bcnt[t] : 0;
    sm[t] = v;
    __syncthreads();
    int acc = v;
    for (int off = 1; off < 1024; off <<= 1) {
        int u = (t >= off) ? sm[t - off] : 0;
        __syncthreads();
        acc += u;
        sm[t] = acc;
        __syncthreads();
    }
    if (t < nbk) { bo[t] = acc - v; bcur[t] = acc - v; }
    if (t == 0) bo[nbk] = e;
}

// ---------------- two-phase pair scatter, packed (src<<7 | dst&127) ----------------
__global__ __launch_bounds__(256) void k_pair2(const int* __restrict__ src, const int* __restrict__ dst,
                                               int* __restrict__ bcur, unsigned int* __restrict__ pairs,
                                               int nbk, int e) {
    __shared__ int cnt[NBK_MAX];
    __shared__ int base[NBK_MAX];
    const int t = threadIdx.x;
    for (int b = t; b < nbk; b += 256) cnt[b] = 0;
    __syncthreads();
    const int e0 = blockIdx.x * EPB;
    int s[16], d[16], lo[16];
    #pragma unroll
    for (int j = 0; j < 16; ++j) {
        int idx = e0 + j * 256 + t;
        if (idx < e) {
            s[j] = src[idx];
            d[j] = dst[idx];
            lo[j] = atomicAdd(&cnt[d[j] >> BSH], 1);
        }
    }
    __syncthreads();
    for (int b = t; b < nbk; b += 256)
        base[b] = cnt[b] ? atomicAdd(&bcur[b], cnt[b]) : 0;
    __syncthreads();
    #pragma unroll
    for (int j = 0; j < 16; ++j) {
        int idx = e0 + j * 256 + t;
        if (idx < e)
            pairs[base[d[j] >> BSH] + lo[j]] = ((unsigned int)s[j] << 7) | (unsigned int)(d[j] & 127);
    }
}

// ---------------- early dinv: per-bucket degree histogram over pairs ----------------
__global__ __launch_bounds__(256) void k_dinv(const unsigned int* __restrict__ pairs,
                                              const int* __restrict__ bo,
                                              float* __restrict__ dinv, int n) {
    __shared__ int cnt[128];
    const int b = blockIdx.x, t = threadIdx.x;
    if (t < 128) cnt[t] = 0;
    __syncthreads();
    const int beg = bo[b], end = bo[b + 1];
    for (int i = beg + t; i < end; i += 256) atomicAdd(&cnt[pairs[i] & 127], 1);
    __syncthreads();
    const int node = (b << BSH) + t;
    if (t < 128 && node < n) dinv[node] = rsqrtf((float)(cnt[t] + 1));   // +1 self loop
}

// ---------------- fused BUILD: gemm blocks [0, ngemm) + CSR blocks [ngemm, ngemm+nbk) ----------------
// gemm output: GROUP-SLICED, dinv-prescaled fp16: hs8[(g*(n+1) + i)*16 + f], g = col>>4.
__global__ __launch_bounds__(512, 4) void k_build(const float* __restrict__ x,
                                                  const _Float16* __restrict__ Wh,
                                                  const float* __restrict__ dinv,
                                                  __half* __restrict__ hs8,
                                                  const unsigned int* __restrict__ pairs,
                                                  const int* __restrict__ bo,
                                                  int* __restrict__ rowptr,
                                                  int* __restrict__ csr_src,
                                                  int n, int e, int ngemm) {
    __shared__ _Float16 Ws[HID][WPAD];   // 67.6 KB (gemm part)
    __shared__ int cnt[128];             // (csr part)
    __shared__ int cur[128];
    const int tid = threadIdx.x;

    if ((int)blockIdx.x >= ngemm) {
        // ---------- CSR part: histogram + scan + rowptr + fill ----------
        const int b = blockIdx.x - ngemm;
        if (tid < 128) cnt[tid] = 0;
        __syncthreads();
        const int beg = bo[b], end = bo[b + 1];
        for (int i = beg + tid; i < end; i += 512)
            atomicAdd(&cnt[pairs[i] & 127], 1);
        __syncthreads();
        if (tid < 128) cur[tid] = cnt[tid];
        __syncthreads();
        for (int off = 1; off < 128; off <<= 1) {
            int u = (tid < 128 && tid >= off) ? cur[tid - off] : 0;
            __syncthreads();
            if (tid < 128) cur[tid] += u;
            __syncthreads();
        }
        int myexcl = 0;
        const int node = (b << BSH) + tid;
        if (tid < 128) {
            myexcl = beg + cur[tid] - cnt[tid];
            if (node < n) rowptr[node] = myexcl;
        }
        if (b == 0 && tid == 0) rowptr[n] = e;
        __syncthreads();
        if (tid < 128) cur[tid] = myexcl;
        __syncthreads();
        for (int i = beg + tid; i < end; i += 512) {
            unsigned int pr = pairs[i];
            int p = atomicAdd(&cur[pr & 127], 1);
            csr_src[p] = (int)(pr >> 7);
        }
        return;
    }

    // ---------- GEMM part: W-in-LDS, barrier-free K-loop, fp16 MFMA, dinv-prescaled ----------
    const int l   = tid & 63;
    const int w   = tid >> 6;            // 0..7
    const int fr  = l & 15;
    const int kg  = l >> 4;
    const int i0  = blockIdx.x * 128 + w * 16;

    const int r0 = i0 + fr;
    const float* xp = &x[(size_t)(r0 < n ? r0 : 0) * FIN + kg * 8];

    float4 xv[8][2];
    #pragma unroll
    for (int ks = 0; ks < 8; ++ks) {
        xv[ks][0] = *(const float4*)&xp[ks * 32];
        xv[ks][1] = *(const float4*)&xp[ks * 32 + 4];
    }

    #pragma unroll
    for (int j = 0; j < 8; ++j) {
        int c    = j * 512 + tid;
        int row  = c >> 5;
        int col8 = c & 31;
        *(half8v*)&Ws[row][col8 * 8] = *(const half8v*)&Wh[row * FIN + col8 * 8];
    }
    __syncthreads();

    f32x4 acc[8] = {};
    #pragma unroll
    for (int ks = 0; ks < 8; ++ks) {
        half8v ha;
        ha[0] = (_Float16)xv[ks][0].x; ha[1] = (_Float16)xv[ks][0].y;
        ha[2] = (_Float16)xv[ks][0].z; ha[3] = (_Float16)xv[ks][0].w;
        ha[4] = (_Float16)xv[ks][1].x; ha[5] = (_Float16)xv[ks][1].y;
        ha[6] = (_Float16)xv[ks][1].z; ha[7] = (_Float16)xv[ks][1].w;
        #pragma unroll
        for (int nt = 0; nt < 8; ++nt) {
            half8v hb = *(const half8v*)&Ws[nt * 16 + fr][kg * 8 + ks * 32];
            acc[nt] = __builtin_amdgcn_mfma_f32_16x16x32_f16(ha, hb, acc[nt], 0, 0, 0);
        }
    }

    // D(m,n): row = kg*4 + reg (M), col = nt*16 + fr (N); group = nt
    int rbase = i0 + kg * 4;
    if (rbase < n) {
        float4 dv = *(const float4*)&dinv[rbase];
        #pragma unroll
        for (int nt = 0; nt < 8; ++nt) {
            f32x4 c = acc[nt];
            #pragma unroll
            for (int r = 0; r < 4; ++r) {
                int gi = rbase + r;
                if (gi < n)
                    hs8[((size_t)nt * (n + 1) + gi) * 16 + fr] =
                        __float2half(((const float*)&c)[r] * ((const float*)&dv)[r]);
            }
        }
    }
}

// ---------------- layer-1 aggregation, group-sliced (XCD-affine) + batched gathers ----------------
// g = blockIdx&7 -> XCD g; slice = 3.2MB (L2-resident). Wave = 1 node of 1 group:
// lane = slot(8) x fpair(8); 8 edges per gather instr, 2 gathers in flight per iter.
__global__ __launch_bounds__(256) void k_agg1(const unsigned int* __restrict__ hs8,
                                              const int* __restrict__ rowptr,
                                              const int* __restrict__ csr_src,
                                              const float* __restrict__ dinv,
                                              const float* __restrict__ b1, const float* __restrict__ W2,
                                              float* __restrict__ zg, int n) {
    const int g = blockIdx.x & 7;
    const int i = (blockIdx.x >> 3) * 4 + (threadIdx.x >> 6);
    if (i >= n) return;
    const int lane = threadIdx.x & 63;
    const int fp   = lane & 7;     // uint (feature pair) within 32B slice
    const int slot = lane >> 3;    // edge sub-slot 0..7
    const unsigned int* base = hs8 + (size_t)g * (n + 1) * 8;

    unsigned int sv = base[((size_t)i << 3) + fp];   // self-loop slice (added post-reduce)
    __half2 acc0 = __float2half2_rn(0.f);
    __half2 acc1 = __float2half2_rn(0.f);

    int e0 = rowptr[i];
    const int end = rowptr[i + 1];
    while (e0 < end) {
        int cnt = end - e0;
        if (cnt > 64) cnt = 64;
        int sidx = (lane < cnt) ? csr_src[e0 + lane] : 0;
        for (int j = 0; j < cnt; j += 16) {
            int j0 = j + slot;
            int j1 = j + 8 + slot;
            int s0 = __shfl(sidx, j0 < cnt ? j0 : 0, 64);
            int s1 = __shfl(sidx, j1 < cnt ? j1 : 0, 64);
            s0 = j0 < cnt ? s0 : n;                      // n = zero row
            s1 = j1 < cnt ? s1 : n;
            unsigned int v0 = base[((size_t)s0 << 3) + fp];
            unsigned int v1 = base[((size_t)s1 << 3) + fp];
            acc0 = __hadd2(acc0, *reinterpret_cast<__half2*>(&v0));
            acc1 = __hadd2(acc1, *reinterpret_cast<__half2*>(&v1));
        }
        e0 += cnt;
    }
    float2 f0 = __half22float2(acc0);
    float2 f1 = __half22float2(acc1);
    float ax = f0.x + f1.x;
    float ay = f0.y + f1.y;
    // reduce the 8 edge slots (lane bits 3..5)
    ax += __shfl_xor(ax, 8, 64);  ay += __shfl_xor(ay, 8, 64);
    ax += __shfl_xor(ax, 16, 64); ay += __shfl_xor(ay, 16, 64);
    ax += __shfl_xor(ax, 32, 64); ay += __shfl_xor(ay, 32, 64);
    // add self-loop once
    float2 sf = __half22float2(*reinterpret_cast<__half2*>(&sv));
    ax += sf.x; ay += sf.y;

    float di = dinv[i];
    float2 bb = ((const float2*)b1)[g * 8 + fp];
    float2 w2 = ((const float2*)W2)[g * 8 + fp];
    float h0 = fmaxf(ax * di + bb.x, 0.f);
    float h1 = fmaxf(ay * di + bb.y, 0.f);
    float z = h0 * w2.x + h1 * w2.y;
    z += __shfl_xor(z, 1, 64);
    z += __shfl_xor(z, 2, 64);
    z += __shfl_xor(z, 4, 64);
    if (lane == 0) zg[(size_t)g * n + i] = z;
}

// ---------------- fold 8 group partials -> zs (pre-scaled by dinv) ----------------
__global__ void k_zsum(const float* __restrict__ zg, const float* __restrict__ dinv,
                       float* __restrict__ zs, int n) {
    int i = blockIdx.x * 256 + threadIdx.x;
    if (i >= n) return;
    float s = 0.f;
    #pragma unroll
    for (int g = 0; g < 8; ++g) s += zg[(size_t)g * n + i];
    zs[i] = s * dinv[i];
}

// ---------------- layer-2 aggregation ----------------
__global__ void k_agg2(const float* __restrict__ zs, const int* __restrict__ rowptr,
                       const int* __restrict__ csr_src, const float* __restrict__ dinv,
                       const float* __restrict__ b2, float* __restrict__ out, int n) {
    int i = blockIdx.x * blockDim.x + threadIdx.x;
    if (i >= n) return;
    float acc = zs[i];
    int beg = rowptr[i], end = rowptr[i + 1];
    for (int e = beg; e < end; ++e) acc += zs[csr_src[e]];
    out[i] = acc * dinv[i] + b2[0];
}

extern "C" void kernel_launch(void* const* d_in, const int* in_sizes, int n_in,
                              void* d_out, int out_size, void* d_ws, size_t ws_size,
                              hipStream_t stream) {
    const float* x  = (const float*)d_in[0];
    const int*   ei = (const int*)d_in[1];
    const float* W1 = (const float*)d_in[2];
    const float* b1 = (const float*)d_in[3];
    const float* W2 = (const float*)d_in[4];
    const float* b2 = (const float*)d_in[5];
    float* out = (float*)d_out;

    const int n = in_sizes[0] / FIN;
    const int e = in_sizes[1] / 2;
    const int* src = ei;
    const int* dst = ei + e;
    const int nbk = (n + (1 << BSH) - 1) >> BSH;
    const int ngemm = (n + 127) / 128;

    char* p = (char*)d_ws;
    auto carve = [&](size_t bytes) { char* q = p; p += (bytes + 255) & ~(size_t)255; return q; };
    int*            bcnt    = (int*)carve((size_t)NBK_MAX * 4);
    int*            bo      = (int*)carve((size_t)(NBK_MAX + 1) * 4);
    int*            bcur    = (int*)carve((size_t)NBK_MAX * 4);
    int*            rowptr  = (int*)carve((size_t)(n + 1) * 4);
    float*          dinv    = (float*)carve((size_t)n * 4);
    int*            csr     = (int*)carve((size_t)e * 4);
    unsigned int*   pairs   = (unsigned int*)carve((size_t)e * 4);
    __half*         hs8     = (__half*)carve((size_t)8 * (n + 1) * 16 * 2);
    float*          zg      = (float*)carve((size_t)8 * n * 4);
    float*          zs      = (float*)carve((size_t)n * 4);
    _Float16*       Wh      = (_Float16*)carve((size_t)HID * FIN * 2);

    const int neb = (e + EPB - 1) / EPB;
    k_whalf<<<(HID * FIN + 255) / 256, 256, 0, stream>>>(W1, Wh, bcnt, (unsigned int*)hs8, n, HID * FIN);
    k_hist <<<neb, 256, 0, stream>>>(dst, bcnt, nbk, e);
    k_bscan<<<1, 1024, 0, stream>>>(bcnt, bo, bcur, nbk, e);
    k_pair2<<<neb, 256, 0, stream>>>(src, dst, bcur, pairs, nbk, e);
    k_dinv <<<nbk, 256, 0, stream>>>(pairs, bo, dinv, n);
    k_build<<<ngemm + nbk, 512, 0, stream>>>(x, Wh, dinv, hs8, pairs, bo, rowptr, csr, n, e, ngemm);
    k_agg1 <<<8 * ((n + 3) / 4), 256, 0, stream>>>((const unsigned int*)hs8, rowptr, csr, dinv, b1, W2, zg, n);
    k_zsum <<<(n + 255) / 256, 256, 0, stream>>>(zg, dinv, zs, n);
    k_agg2 <<<(n + 255) / 256, 256, 0, stream>>>(zs, rowptr, csr, dinv, b2, out, n);
}

// Round 18
// 211.450 us; speedup vs baseline: 1.3860x; 1.3860x over previous
//
#include <hip/hip_runtime.h>
#include <hip/hip_bf16.h>
#include <hip/hip_fp16.h>

#define FIN 256
#define HID 128
#define BSH 7            // bucket = dst >> 7 (128 nodes/bucket)
#define NBK_MAX 1024
#define EPB 4096         // edges per block in hist/pair kernels
#define WPAD 264         // 256 + 8 halfs row pad

typedef __attribute__((ext_vector_type(8))) _Float16 half8v;  // f16x8 MFMA frag (4 VGPRs)
typedef __attribute__((ext_vector_type(4))) float f32x4;      // MFMA acc

// ---------------- W1 -> fp16 (once) + bcnt & deg zeroing ----------------
__global__ void k_whalf(const float* __restrict__ W1, _Float16* __restrict__ Wh,
                        int* __restrict__ bcnt, int* __restrict__ deg,
                        int n, int total) {
    int i = blockIdx.x * 256 + threadIdx.x;
    if (i < total) Wh[i] = (_Float16)W1[i];
    if (blockIdx.x == 0) {
        #pragma unroll
        for (int j = 0; j < NBK_MAX; j += 256) bcnt[j + threadIdx.x] = 0;
    }
    const int stride = gridDim.x * 256;
    for (int j = i; j < n; j += stride) deg[j] = 0;
}

// ---------------- bucket histogram (LDS) + per-node degree (global atomics) ----------------
__global__ __launch_bounds__(256) void k_hist(const int* __restrict__ dst, int* __restrict__ bcnt,
                                              int* __restrict__ deg, int nbk, int e) {
    __shared__ int cnt[NBK_MAX];
    int t = threadIdx.x;
    for (int b = t; b < nbk; b += 256) cnt[b] = 0;
    __syncthreads();
    int e0 = blockIdx.x * EPB;
    #pragma unroll
    for (int j = 0; j < EPB; j += 256) {
        int idx = e0 + j + t;
        if (idx < e) {
            int d = dst[idx];
            atomicAdd(&cnt[d >> BSH], 1);
            atomicAdd(&deg[d], 1);
        }
    }
    __syncthreads();
    for (int b = t; b < nbk; b += 256)
        if (cnt[b]) atomicAdd(&bcnt[b], cnt[b]);
}

// ---------------- bucket scan (single block) ----------------
__global__ __launch_bounds__(1024) void k_bscan(const int* __restrict__ bcnt, int* __restrict__ bo,
                                                int* __restrict__ bcur, int nbk, int e) {
    __shared__ int sm[1024];
    int t = threadIdx.x;
    int v = (t < nbk) ? bcnt[t] : 0;
    sm[t] = v;
    __syncthreads();
    int acc = v;
    for (int off = 1; off < 1024; off <<= 1) {
        int u = (t >= off) ? sm[t - off] : 0;
        __syncthreads();
        acc += u;
        sm[t] = acc;
        __syncthreads();
    }
    if (t < nbk) { bo[t] = acc - v; bcur[t] = acc - v; }
    if (t == 0) bo[nbk] = e;
}

// ---------------- two-phase pair scatter + fused deg->dinv conversion ----------------
__global__ __launch_bounds__(256) void k_pair2(const int* __restrict__ src, const int* __restrict__ dst,
                                               int* __restrict__ bcur, unsigned int* __restrict__ pairs,
                                               const int* __restrict__ deg, float* __restrict__ dinv,
                                               int nbk, int n, int e) {
    // deg is complete (k_hist done): convert to dinv, grid-strided, no sync needed
    for (int idx = blockIdx.x * 256 + threadIdx.x; idx < n; idx += gridDim.x * 256)
        dinv[idx] = rsqrtf((float)(deg[idx] + 1));   // +1 self loop

    __shared__ int cnt[NBK_MAX];
    __shared__ int base[NBK_MAX];
    const int t = threadIdx.x;
    for (int b = t; b < nbk; b += 256) cnt[b] = 0;
    __syncthreads();
    const int e0 = blockIdx.x * EPB;
    int s[16], d[16], lo[16];
    #pragma unroll
    for (int j = 0; j < 16; ++j) {
        int idx = e0 + j * 256 + t;
        if (idx < e) {
            s[j] = src[idx];
            d[j] = dst[idx];
            lo[j] = atomicAdd(&cnt[d[j] >> BSH], 1);
        }
    }
    __syncthreads();
    for (int b = t; b < nbk; b += 256)
        base[b] = cnt[b] ? atomicAdd(&bcur[b], cnt[b]) : 0;
    __syncthreads();
    #pragma unroll
    for (int j = 0; j < 16; ++j) {
        int idx = e0 + j * 256 + t;
        if (idx < e)
            pairs[base[d[j] >> BSH] + lo[j]] = ((unsigned int)s[j] << 7) | (unsigned int)(d[j] & 127);
    }
}

// ---------------- fused BUILD: gemm blocks [0, ngemm) + CSR blocks [ngemm, ngemm+nbk) ----------------
// gemm: W-in-LDS, barrier-free K-loop, fp16 MFMA, dinv-PRESCALED plain hs[n][128].
__global__ __launch_bounds__(512, 4) void k_build(const float* __restrict__ x,
                                                  const _Float16* __restrict__ Wh,
                                                  const float* __restrict__ dinv,
                                                  __half* __restrict__ hs,
                                                  const unsigned int* __restrict__ pairs,
                                                  const int* __restrict__ bo,
                                                  int* __restrict__ rowptr,
                                                  int* __restrict__ csr_src,
                                                  int n, int e, int ngemm) {
    __shared__ _Float16 Ws[HID][WPAD];   // 67.6 KB (gemm part)
    __shared__ int cnt[128];             // (csr part)
    __shared__ int cur[128];
    const int tid = threadIdx.x;

    if ((int)blockIdx.x >= ngemm) {
        // ---------- CSR part: histogram + scan + rowptr + fill ----------
        const int b = blockIdx.x - ngemm;
        if (tid < 128) cnt[tid] = 0;
        __syncthreads();
        const int beg = bo[b], end = bo[b + 1];
        for (int i = beg + tid; i < end; i += 512)
            atomicAdd(&cnt[pairs[i] & 127], 1);
        __syncthreads();
        if (tid < 128) cur[tid] = cnt[tid];
        __syncthreads();
        for (int off = 1; off < 128; off <<= 1) {
            int u = (tid < 128 && tid >= off) ? cur[tid - off] : 0;
            __syncthreads();
            if (tid < 128) cur[tid] += u;
            __syncthreads();
        }
        int myexcl = 0;
        const int node = (b << BSH) + tid;
        if (tid < 128) {
            myexcl = beg + cur[tid] - cnt[tid];
            if (node < n) rowptr[node] = myexcl;
        }
        if (b == 0 && tid == 0) rowptr[n] = e;
        __syncthreads();
        if (tid < 128) cur[tid] = myexcl;
        __syncthreads();
        for (int i = beg + tid; i < end; i += 512) {
            unsigned int pr = pairs[i];
            int p = atomicAdd(&cur[pr & 127], 1);
            csr_src[p] = (int)(pr >> 7);
        }
        return;
    }

    // ---------- GEMM part ----------
    const int l   = tid & 63;
    const int w   = tid >> 6;            // 0..7
    const int fr  = l & 15;
    const int kg  = l >> 4;
    const int i0  = blockIdx.x * 128 + w * 16;

    const int r0 = i0 + fr;
    const float* xp = &x[(size_t)(r0 < n ? r0 : 0) * FIN + kg * 8];

    float4 xv[8][2];
    #pragma unroll
    for (int ks = 0; ks < 8; ++ks) {
        xv[ks][0] = *(const float4*)&xp[ks * 32];
        xv[ks][1] = *(const float4*)&xp[ks * 32 + 4];
    }

    #pragma unroll
    for (int j = 0; j < 8; ++j) {
        int c    = j * 512 + tid;
        int row  = c >> 5;
        int col8 = c & 31;
        *(half8v*)&Ws[row][col8 * 8] = *(const half8v*)&Wh[row * FIN + col8 * 8];
    }
    __syncthreads();

    f32x4 acc[8] = {};
    #pragma unroll
    for (int ks = 0; ks < 8; ++ks) {
        half8v ha;
        ha[0] = (_Float16)xv[ks][0].x; ha[1] = (_Float16)xv[ks][0].y;
        ha[2] = (_Float16)xv[ks][0].z; ha[3] = (_Float16)xv[ks][0].w;
        ha[4] = (_Float16)xv[ks][1].x; ha[5] = (_Float16)xv[ks][1].y;
        ha[6] = (_Float16)xv[ks][1].z; ha[7] = (_Float16)xv[ks][1].w;
        #pragma unroll
        for (int nt = 0; nt < 8; ++nt) {
            half8v hb = *(const half8v*)&Ws[nt * 16 + fr][kg * 8 + ks * 32];
            acc[nt] = __builtin_amdgcn_mfma_f32_16x16x32_f16(ha, hb, acc[nt], 0, 0, 0);
        }
    }

    // D(m,n): row = kg*4 + reg (M), col = nt*16 + fr (N)
    int rbase = i0 + kg * 4;
    if (rbase < n) {
        float4 dv = *(const float4*)&dinv[rbase];
        #pragma unroll
        for (int nt = 0; nt < 8; ++nt) {
            f32x4 c = acc[nt];
            int col = nt * 16 + fr;
            #pragma unroll
            for (int r = 0; r < 4; ++r) {
                int gi = rbase + r;
                if (gi < n)
                    hs[(size_t)gi * HID + col] = __float2half(((const float*)&c)[r] * ((const float*)&dv)[r]);
            }
        }
    }
}

// ---------------- layer-1 aggregation fused with layer-2 dot (round-14 form) ----------------
// one wave per node; scalarized edge stream (SGPR node id, s_load csr, SGPR-base gathers);
// 8 gathers in flight, packed fp16 accumulation.
__global__ __launch_bounds__(256) void k_agg1(const unsigned int* __restrict__ hs,
                                              const int* __restrict__ rowptr,
                                              const int* __restrict__ csr_src,
                                              const float* __restrict__ dinv,
                                              const float* __restrict__ b1, const float* __restrict__ W2,
                                              float* __restrict__ zs, int n) {
    const int i = __builtin_amdgcn_readfirstlane((blockIdx.x << 2) + (threadIdx.x >> 6));
    if (i >= n) return;
    const int lane = threadIdx.x & 63;

    unsigned int sv = hs[((size_t)i << 6) + lane];         // self-loop term (prescaled)
    float2 sf = __half22float2(*reinterpret_cast<__half2*>(&sv));
    float ax = sf.x, ay = sf.y;

    __half2 acc0 = __float2half2_rn(0.f);
    __half2 acc1 = __float2half2_rn(0.f);

    const int beg = rowptr[i];
    const int end = rowptr[i + 1];
    int j = beg;
    for (; j + 8 <= end; j += 8) {
        unsigned int v[8];
        #pragma unroll
        for (int k = 0; k < 8; ++k) {
            int s = csr_src[j + k];                        // uniform -> s_load
            v[k] = hs[((size_t)s << 6) + lane];            // SGPR base + lane offset
        }
        #pragma unroll
        for (int k = 0; k < 8; ++k) {
            __half2 hv = *reinterpret_cast<__half2*>(&v[k]);
            if (k & 1) acc1 = __hadd2(acc1, hv);
            else       acc0 = __hadd2(acc0, hv);
        }
    }
    for (; j < end; ++j) {
        int s = csr_src[j];
        unsigned int v = hs[((size_t)s << 6) + lane];
        acc0 = __hadd2(acc0, *reinterpret_cast<__half2*>(&v));
    }

    float2 f0 = __half22float2(acc0);
    float2 f1 = __half22float2(acc1);
    ax += f0.x + f1.x;
    ay += f0.y + f1.y;

    float di = dinv[i];
    float2 bb = ((const float2*)b1)[lane];
    float h0 = fmaxf(ax * di + bb.x, 0.f);
    float h1 = fmaxf(ay * di + bb.y, 0.f);
    float2 w2 = ((const float2*)W2)[lane];
    float z = h0 * w2.x + h1 * w2.y;
    #pragma unroll
    for (int off = 32; off; off >>= 1) z += __shfl_xor(z, off, 64);
    if (lane == 0) zs[i] = z * di;
}

// ---------------- layer-2 aggregation ----------------
__global__ void k_agg2(const float* __restrict__ zs, const int* __restrict__ rowptr,
                       const int* __restrict__ csr_src, const float* __restrict__ dinv,
                       const float* __restrict__ b2, float* __restrict__ out, int n) {
    int i = blockIdx.x * blockDim.x + threadIdx.x;
    if (i >= n) return;
    float acc = zs[i];
    int beg = rowptr[i], end = rowptr[i + 1];
    for (int e = beg; e < end; ++e) acc += zs[csr_src[e]];
    out[i] = acc * dinv[i] + b2[0];
}

extern "C" void kernel_launch(void* const* d_in, const int* in_sizes, int n_in,
                              void* d_out, int out_size, void* d_ws, size_t ws_size,
                              hipStream_t stream) {
    const float* x  = (const float*)d_in[0];
    const int*   ei = (const int*)d_in[1];
    const float* W1 = (const float*)d_in[2];
    const float* b1 = (const float*)d_in[3];
    const float* W2 = (const float*)d_in[4];
    const float* b2 = (const float*)d_in[5];
    float* out = (float*)d_out;

    const int n = in_sizes[0] / FIN;
    const int e = in_sizes[1] / 2;
    const int* src = ei;
    const int* dst = ei + e;
    const int nbk = (n + (1 << BSH) - 1) >> BSH;
    const int ngemm = (n + 127) / 128;

    char* p = (char*)d_ws;
    auto carve = [&](size_t bytes) { char* q = p; p += (bytes + 255) & ~(size_t)255; return q; };
    int*            bcnt    = (int*)carve((size_t)NBK_MAX * 4);
    int*            bo      = (int*)carve((size_t)(NBK_MAX + 1) * 4);
    int*            bcur    = (int*)carve((size_t)NBK_MAX * 4);
    int*            rowptr  = (int*)carve((size_t)(n + 1) * 4);
    float*          dinv    = (float*)carve((size_t)n * 4);
    int*            deg     = (int*)carve((size_t)n * 4);
    int*            csr     = (int*)carve((size_t)e * 4);
    unsigned int*   pairs   = (unsigned int*)carve((size_t)e * 4);
    __half*         hs      = (__half*)carve((size_t)n * HID * 2);
    float*          zs      = (float*)carve((size_t)n * 4);
    _Float16*       Wh      = (_Float16*)carve((size_t)HID * FIN * 2);

    const int neb = (e + EPB - 1) / EPB;
    k_whalf<<<(HID * FIN + 255) / 256, 256, 0, stream>>>(W1, Wh, bcnt, deg, n, HID * FIN);
    k_hist <<<neb, 256, 0, stream>>>(dst, bcnt, deg, nbk, e);
    k_bscan<<<1, 1024, 0, stream>>>(bcnt, bo, bcur, nbk, e);
    k_pair2<<<neb, 256, 0, stream>>>(src, dst, bcur, pairs, deg, dinv, nbk, n, e);
    k_build<<<ngemm + nbk, 512, 0, stream>>>(x, Wh, dinv, hs, pairs, bo, rowptr, csr, n, e, ngemm);
    k_agg1 <<<(n + 3) / 4, 256, 0, stream>>>((const unsigned int*)hs, rowptr, csr, dinv, b1, W2, zs, n);
    k_agg2 <<<(n + 255) / 256, 256, 0, stream>>>(zs, rowptr, csr, dinv, b2, out, n);
}

// Round 19
// 157.611 us; speedup vs baseline: 1.8594x; 1.3416x over previous
//
#include <hip/hip_runtime.h>
#include <hip/hip_bf16.h>
#include <hip/hip_fp16.h>

#define FIN 256
#define HID 128
#define BSH 7            // bucket = dst >> 7 (128 nodes/bucket)
#define NBK_MAX 1024
#define EPB 4096         // edges per block in hist/pair kernels
#define WPAD 264         // 256 + 8 halfs row pad

typedef __attribute__((ext_vector_type(8))) _Float16 half8v;  // f16x8 MFMA frag (4 VGPRs)
typedef __attribute__((ext_vector_type(4))) float f32x4;      // MFMA acc

// ---------------- W1 -> fp16 (once) + bcnt zeroing ----------------
__global__ void k_whalf(const float* __restrict__ W1, _Float16* __restrict__ Wh,
                        int* __restrict__ bcnt, int total) {
    int i = blockIdx.x * 256 + threadIdx.x;
    if (i < total) Wh[i] = (_Float16)W1[i];
    if (blockIdx.x == 0) {
        #pragma unroll
        for (int j = 0; j < NBK_MAX; j += 256) bcnt[j + threadIdx.x] = 0;
    }
}

// ---------------- bucket histogram via LDS (391 blocks: flush atomics stay rare) ----------------
__global__ __launch_bounds__(256) void k_hist(const int* __restrict__ dst, int* __restrict__ bcnt,
                                              int nbk, int e) {
    __shared__ int cnt[NBK_MAX];
    int t = threadIdx.x;
    for (int b = t; b < nbk; b += 256) cnt[b] = 0;
    __syncthreads();
    int e0 = blockIdx.x * EPB;
    #pragma unroll
    for (int j = 0; j < EPB; j += 256) {
        int idx = e0 + j + t;
        if (idx < e) atomicAdd(&cnt[dst[idx] >> BSH], 1);
    }
    __syncthreads();
    for (int b = t; b < nbk; b += 256)
        if (cnt[b]) atomicAdd(&bcnt[b], cnt[b]);
}

// ---------------- bucket scan (single block) ----------------
__global__ __launch_bounds__(1024) void k_bscan(const int* __restrict__ bcnt, int* __restrict__ bo,
                                                int* __restrict__ bcur, int nbk, int e) {
    __shared__ int sm[1024];
    int t = threadIdx.x;
    int v = (t < nbk) ? bcnt[t] : 0;
    sm[t] = v;
    __syncthreads();
    int acc = v;
    for (int off = 1; off < 1024; off <<= 1) {
        int u = (t >= off) ? sm[t - off] : 0;
        __syncthreads();
        acc += u;
        sm[t] = acc;
        __syncthreads();
    }
    if (t < nbk) { bo[t] = acc - v; bcur[t] = acc - v; }
    if (t == 0) bo[nbk] = e;
}

// ---------------- two-phase pair scatter, packed (src<<7 | dst&127) ----------------
__global__ __launch_bounds__(256) void k_pair2(const int* __restrict__ src, const int* __restrict__ dst,
                                               int* __restrict__ bcur, unsigned int* __restrict__ pairs,
                                               int nbk, int e) {
    __shared__ int cnt[NBK_MAX];
    __shared__ int base[NBK_MAX];
    const int t = threadIdx.x;
    for (int b = t; b < nbk; b += 256) cnt[b] = 0;
    __syncthreads();
    const int e0 = blockIdx.x * EPB;
    int s[16], d[16], lo[16];
    #pragma unroll
    for (int j = 0; j < 16; ++j) {
        int idx = e0 + j * 256 + t;
        if (idx < e) {
            s[j] = src[idx];
            d[j] = dst[idx];
            lo[j] = atomicAdd(&cnt[d[j] >> BSH], 1);
        }
    }
    __syncthreads();
    for (int b = t; b < nbk; b += 256)
        base[b] = cnt[b] ? atomicAdd(&bcur[b], cnt[b]) : 0;
    __syncthreads();
    #pragma unroll
    for (int j = 0; j < 16; ++j) {
        int idx = e0 + j * 256 + t;
        if (idx < e)
            pairs[base[d[j] >> BSH] + lo[j]] = ((unsigned int)s[j] << 7) | (unsigned int)(d[j] & 127);
    }
}

// ---------------- early dinv: per-bucket degree histogram over pairs (LDS atomics only) ----------------
__global__ __launch_bounds__(256) void k_dinv(const unsigned int* __restrict__ pairs,
                                              const int* __restrict__ bo,
                                              float* __restrict__ dinv, int n) {
    __shared__ int cnt[128];
    const int b = blockIdx.x, t = threadIdx.x;
    if (t < 128) cnt[t] = 0;
    __syncthreads();
    const int beg = bo[b], end = bo[b + 1];
    for (int i = beg + t; i < end; i += 256) atomicAdd(&cnt[pairs[i] & 127], 1);
    __syncthreads();
    const int node = (b << BSH) + t;
    if (t < 128 && node < n) dinv[node] = rsqrtf((float)(cnt[t] + 1));   // +1 self loop
}

// ---------------- fused BUILD: gemm blocks [0, ngemm) + CSR blocks [ngemm, ngemm+nbk) ----------------
// gemm: W-in-LDS, barrier-free K-loop, fp16 MFMA, dinv-PRESCALED plain hs[n][128].
__global__ __launch_bounds__(512, 4) void k_build(const float* __restrict__ x,
                                                  const _Float16* __restrict__ Wh,
                                                  const float* __restrict__ dinv,
                                                  __half* __restrict__ hs,
                                                  const unsigned int* __restrict__ pairs,
                                                  const int* __restrict__ bo,
                                                  int* __restrict__ rowptr,
                                                  int* __restrict__ csr_src,
                                                  int n, int e, int ngemm) {
    __shared__ _Float16 Ws[HID][WPAD];   // 67.6 KB (gemm part)
    __shared__ int cnt[128];             // (csr part)
    __shared__ int cur[128];
    const int tid = threadIdx.x;

    if ((int)blockIdx.x >= ngemm) {
        // ---------- CSR part: histogram + scan + rowptr + fill ----------
        const int b = blockIdx.x - ngemm;
        if (tid < 128) cnt[tid] = 0;
        __syncthreads();
        const int beg = bo[b], end = bo[b + 1];
        for (int i = beg + tid; i < end; i += 512)
            atomicAdd(&cnt[pairs[i] & 127], 1);
        __syncthreads();
        if (tid < 128) cur[tid] = cnt[tid];
        __syncthreads();
        for (int off = 1; off < 128; off <<= 1) {
            int u = (tid < 128 && tid >= off) ? cur[tid - off] : 0;
            __syncthreads();
            if (tid < 128) cur[tid] += u;
            __syncthreads();
        }
        int myexcl = 0;
        const int node = (b << BSH) + tid;
        if (tid < 128) {
            myexcl = beg + cur[tid] - cnt[tid];
            if (node < n) rowptr[node] = myexcl;
        }
        if (b == 0 && tid == 0) rowptr[n] = e;
        __syncthreads();
        if (tid < 128) cur[tid] = myexcl;
        __syncthreads();
        for (int i = beg + tid; i < end; i += 512) {
            unsigned int pr = pairs[i];
            int p = atomicAdd(&cur[pr & 127], 1);
            csr_src[p] = (int)(pr >> 7);
        }
        return;
    }

    // ---------- GEMM part ----------
    const int l   = tid & 63;
    const int w   = tid >> 6;            // 0..7
    const int fr  = l & 15;
    const int kg  = l >> 4;
    const int i0  = blockIdx.x * 128 + w * 16;

    const int r0 = i0 + fr;
    const float* xp = &x[(size_t)(r0 < n ? r0 : 0) * FIN + kg * 8];

    float4 xv[8][2];
    #pragma unroll
    for (int ks = 0; ks < 8; ++ks) {
        xv[ks][0] = *(const float4*)&xp[ks * 32];
        xv[ks][1] = *(const float4*)&xp[ks * 32 + 4];
    }

    #pragma unroll
    for (int j = 0; j < 8; ++j) {
        int c    = j * 512 + tid;
        int row  = c >> 5;
        int col8 = c & 31;
        *(half8v*)&Ws[row][col8 * 8] = *(const half8v*)&Wh[row * FIN + col8 * 8];
    }
    __syncthreads();

    f32x4 acc[8] = {};
    #pragma unroll
    for (int ks = 0; ks < 8; ++ks) {
        half8v ha;
        ha[0] = (_Float16)xv[ks][0].x; ha[1] = (_Float16)xv[ks][0].y;
        ha[2] = (_Float16)xv[ks][0].z; ha[3] = (_Float16)xv[ks][0].w;
        ha[4] = (_Float16)xv[ks][1].x; ha[5] = (_Float16)xv[ks][1].y;
        ha[6] = (_Float16)xv[ks][1].z; ha[7] = (_Float16)xv[ks][1].w;
        #pragma unroll
        for (int nt = 0; nt < 8; ++nt) {
            half8v hb = *(const half8v*)&Ws[nt * 16 + fr][kg * 8 + ks * 32];
            acc[nt] = __builtin_amdgcn_mfma_f32_16x16x32_f16(ha, hb, acc[nt], 0, 0, 0);
        }
    }

    // D(m,n): row = kg*4 + reg (M), col = nt*16 + fr (N)
    int rbase = i0 + kg * 4;
    if (rbase < n) {
        float4 dv = *(const float4*)&dinv[rbase];
        #pragma unroll
        for (int nt = 0; nt < 8; ++nt) {
            f32x4 c = acc[nt];
            int col = nt * 16 + fr;
            #pragma unroll
            for (int r = 0; r < 4; ++r) {
                int gi = rbase + r;
                if (gi < n)
                    hs[(size_t)gi * HID + col] = __float2half(((const float*)&c)[r] * ((const float*)&dv)[r]);
            }
        }
    }
}

// ---------------- layer-1 aggregation fused with layer-2 dot (round-14 form) ----------------
// one wave per node; scalarized edge stream; 8 gathers in flight, packed fp16 accumulation.
__global__ __launch_bounds__(256) void k_agg1(const unsigned int* __restrict__ hs,
                                              const int* __restrict__ rowptr,
                                              const int* __restrict__ csr_src,
                                              const float* __restrict__ dinv,
                                              const float* __restrict__ b1, const float* __restrict__ W2,
                                              float* __restrict__ zs, int n) {
    const int i = __builtin_amdgcn_readfirstlane((blockIdx.x << 2) + (threadIdx.x >> 6));
    if (i >= n) return;
    const int lane = threadIdx.x & 63;

    unsigned int sv = hs[((size_t)i << 6) + lane];         // self-loop term (prescaled)
    float2 sf = __half22float2(*reinterpret_cast<__half2*>(&sv));
    float ax = sf.x, ay = sf.y;

    __half2 acc0 = __float2half2_rn(0.f);
    __half2 acc1 = __float2half2_rn(0.f);

    const int beg = rowptr[i];
    const int end = rowptr[i + 1];
    int j = beg;
    for (; j + 8 <= end; j += 8) {
        unsigned int v[8];
        #pragma unroll
        for (int k = 0; k < 8; ++k) {
            int s = csr_src[j + k];                        // uniform -> s_load
            v[k] = hs[((size_t)s << 6) + lane];            // SGPR base + lane offset
        }
        #pragma unroll
        for (int k = 0; k < 8; ++k) {
            __half2 hv = *reinterpret_cast<__half2*>(&v[k]);
            if (k & 1) acc1 = __hadd2(acc1, hv);
            else       acc0 = __hadd2(acc0, hv);
        }
    }
    for (; j < end; ++j) {
        int s = csr_src[j];
        unsigned int v = hs[((size_t)s << 6) + lane];
        acc0 = __hadd2(acc0, *reinterpret_cast<__half2*>(&v));
    }

    float2 f0 = __half22float2(acc0);
    float2 f1 = __half22float2(acc1);
    ax += f0.x + f1.x;
    ay += f0.y + f1.y;

    float di = dinv[i];
    float2 bb = ((const float2*)b1)[lane];
    float h0 = fmaxf(ax * di + bb.x, 0.f);
    float h1 = fmaxf(ay * di + bb.y, 0.f);
    float2 w2 = ((const float2*)W2)[lane];
    float z = h0 * w2.x + h1 * w2.y;
    #pragma unroll
    for (int off = 32; off; off >>= 1) z += __shfl_xor(z, off, 64);
    if (lane == 0) zs[i] = z * di;
}

// ---------------- layer-2 aggregation ----------------
__global__ void k_agg2(const float* __restrict__ zs, const int* __restrict__ rowptr,
                       const int* __restrict__ csr_src, const float* __restrict__ dinv,
                       const float* __restrict__ b2, float* __restrict__ out, int n) {
    int i = blockIdx.x * blockDim.x + threadIdx.x;
    if (i >= n) return;
    float acc = zs[i];
    int beg = rowptr[i], end = rowptr[i + 1];
    for (int e = beg; e < end; ++e) acc += zs[csr_src[e]];
    out[i] = acc * dinv[i] + b2[0];
}

extern "C" void kernel_launch(void* const* d_in, const int* in_sizes, int n_in,
                              void* d_out, int out_size, void* d_ws, size_t ws_size,
                              hipStream_t stream) {
    const float* x  = (const float*)d_in[0];
    const int*   ei = (const int*)d_in[1];
    const float* W1 = (const float*)d_in[2];
    const float* b1 = (const float*)d_in[3];
    const float* W2 = (const float*)d_in[4];
    const float* b2 = (const float*)d_in[5];
    float* out = (float*)d_out;

    const int n = in_sizes[0] / FIN;
    const int e = in_sizes[1] / 2;
    const int* src = ei;
    const int* dst = ei + e;
    const int nbk = (n + (1 << BSH) - 1) >> BSH;
    const int ngemm = (n + 127) / 128;

    char* p = (char*)d_ws;
    auto carve = [&](size_t bytes) { char* q = p; p += (bytes + 255) & ~(size_t)255; return q; };
    int*            bcnt    = (int*)carve((size_t)NBK_MAX * 4);
    int*            bo      = (int*)carve((size_t)(NBK_MAX + 1) * 4);
    int*            bcur    = (int*)carve((size_t)NBK_MAX * 4);
    int*            rowptr  = (int*)carve((size_t)(n + 1) * 4);
    float*          dinv    = (float*)carve((size_t)n * 4);
    int*            csr     = (int*)carve((size_t)e * 4);
    unsigned int*   pairs   = (unsigned int*)carve((size_t)e * 4);
    __half*         hs      = (__half*)carve((size_t)n * HID * 2);
    float*          zs      = (float*)carve((size_t)n * 4);
    _Float16*       Wh      = (_Float16*)carve((size_t)HID * FIN * 2);

    const int neb = (e + EPB - 1) / EPB;
    k_whalf<<<(HID * FIN + 255) / 256, 256, 0, stream>>>(W1, Wh, bcnt, HID * FIN);
    k_hist <<<neb, 256, 0, stream>>>(dst, bcnt, nbk, e);
    k_bscan<<<1, 1024, 0, stream>>>(bcnt, bo, bcur, nbk, e);
    k_pair2<<<neb, 256, 0, stream>>>(src, dst, bcur, pairs, nbk, e);
    k_dinv <<<nbk, 256, 0, stream>>>(pairs, bo, dinv, n);
    k_build<<<ngemm + nbk, 512, 0, stream>>>(x, Wh, dinv, hs, pairs, bo, rowptr, csr, n, e, ngemm);
    k_agg1 <<<(n + 3) / 4, 256, 0, stream>>>((const unsigned int*)hs, rowptr, csr, dinv, b1, W2, zs, n);
    k_agg2 <<<(n + 255) / 256, 256, 0, stream>>>(zs, rowptr, csr, dinv, b2, out, n);
}